// Round 3
// baseline (175.525 us; speedup 1.0000x reference)
//
#include <hip/hip_runtime.h>
#include <hip/hip_bf16.h>
#include <math.h>

// Problem constants
#define D_BINS 59
#define CTX    80
#define O_TOT  139
#define O_PAD  144      // padded to 9 MFMA row-tiles
#define K_CIN  256
#define PIXELS 704
#define BNPAIR 24
#define BEVHW  16384
#define NBATCH 4

// BEV binning: tile = 8 rows x 16 cols -> 128 cells, 128 tiles/batch.
#define NTILE   128
#define NBUCKET (NBATCH * NTILE)   // 512
#define TCELLS  128

// gemm blocks: 32 px each -> 528 blocks, 256 threads (4 waves).
#define PXT    32
#define NPXT   22                  // 704/32
#define NBLK   (BNPAIR * NPXT)     // 528
#define SEGS   (6 * NPXT)          // 132 segments per bucket
#define EPB    (PXT * D_BINS)      // 1888 entries per block region

#define CAP    2816
#define CAPP   (CAP + TCELLS * 7)

// Pre-converted operand slabs (bf16 hi/lo, swizzled == LDS layout):
// W per k-step: 2 planes * 144 rows * 64 B = 18432, padded to 20480 B.
// I per (block, k-step): 2 planes * 32 px * 64 B = 4096 B.
#define WSLAB  20480
#define ISLAB  4096

// Workspace layout (4B units)
#define WHL_OFF    0
#define WHL_F      (8 * WSLAB / 4)                 // 40,960
#define IMGHL_OFF  (WHL_OFF + WHL_F)
#define IMGHL_F    (NBLK * 8 * ISLAB / 4)          // 4,325,376
#define CTX_OFF    (IMGHL_OFF + IMGHL_F)
#define CTX_F      (BNPAIR * PIXELS * CTX / 2)     // 675,840
#define CNTMAT_OFF (CTX_OFF + CTX_F)
#define OFSMAT_OFF (CNTMAT_OFF + NBLK * NTILE)
#define PLIST_OFF  (OFSMAT_OFF + NBLK * NTILE)     // even -> uint2 aligned

typedef __attribute__((ext_vector_type(8))) short bf16x8;
typedef __attribute__((ext_vector_type(4))) float f32x4;

__device__ __forceinline__ unsigned short f2bf(float v) {
    __hip_bfloat16 h = __float2bfloat16(v);   // RNE
    return *reinterpret_cast<unsigned short*>(&h);
}
__device__ __forceinline__ float bf2f(unsigned short u) {
    return __uint_as_float(((unsigned)u) << 16);
}

// ---------------------------------------------------------------------------
// Kernel 0 (prep): blocks 0..143 split W into bf16 hi/lo, k-sliced+swizzled
// (layout [ks][pl][row][granule-swizzled 64B], pad rows/zones zeroed).
// Blocks 144..671 convert img (bn,pt) slab to bf16 hi/lo in the exact
// per-k-step LDS layout [pl][px][gs*16 + 2*(k&7)] so gemm staging is a
// layout-identity copy.
// ---------------------------------------------------------------------------
__global__ __launch_bounds__(256) void prep_kernel(
    const float* __restrict__ img,           // (24, 256, 704)
    const float* __restrict__ w,             // (139, 256)
    unsigned short* __restrict__ whl2,       // [8][WSLAB/2]
    unsigned short* __restrict__ imghl)      // [528][8][ISLAB/2]
{
    const int tid = threadIdx.x;
    if (blockIdx.x < O_PAD) {
        const int row = blockIdx.x;
        const float v = (row < O_TOT) ? w[(size_t)row * K_CIN + tid] : 0.f;
        const unsigned short hi = f2bf(v);
        const unsigned short lo = f2bf(v - bf2f(hi));
        const int ks = tid >> 5, kk = tid & 31;
        const int g = kk >> 3, e = kk & 7;
        const int gs = g ^ ((row >> 1) & 3);
        const size_t base = (size_t)ks * (WSLAB / 2) + row * 32 + gs * 8 + e;
        whl2[base]        = hi;
        whl2[base + 4608] = lo;                   // plane stride 9216 B
        if (row < 8) {                             // zero the 2 KB pad of ks=row
            for (int i = tid; i < 1024; i += 256)
                whl2[(size_t)row * (WSLAB / 2) + 9216 + i] = 0;
        }
    } else {
        __shared__ unsigned short sbuf[ISLAB / 2];
        const int id = blockIdx.x - O_PAD;        // 0..527
        const int bn = id / NPXT, pt = id - bn * NPXT;
        const float* ib = img + (size_t)bn * K_CIN * PIXELS + pt * PXT;
        for (int ks = 0; ks < 8; ++ks) {
            const int kk  = tid >> 3;             // 0..31
            const int px4 = (tid & 7) * 4;
            const float4 v = *(const float4*)&ib[(size_t)(ks * 32 + kk) * PIXELS + px4];
            const float a[4] = {v.x, v.y, v.z, v.w};
            const int g = kk >> 3, e = kk & 7;
#pragma unroll
            for (int j = 0; j < 4; ++j) {
                const int px = px4 + j;
                const int gs = g ^ ((px >> 1) & 3);
                const unsigned short hi = f2bf(a[j]);
                const unsigned short lo = f2bf(a[j] - bf2f(hi));
                sbuf[px * 32 + gs * 8 + e]        = hi;
                sbuf[1024 + px * 32 + gs * 8 + e] = lo;   // plane stride 2048 B
            }
            __syncthreads();
            unsigned short* ob = imghl + ((size_t)id * 8 + ks) * (ISLAB / 2);
            *(float4*)&ob[tid * 8] = *(const float4*)&sbuf[tid * 8];
            __syncthreads();
        }
    }
}

// ---------------------------------------------------------------------------
// Kernel 1: MFMA GEMM + fused softmax/binning. 256 threads = 4 waves:
// wave w -> px-sub s=w&1 (16 px), o-half h=w>>1 (h0: rows 0..79, h1: 80..143).
// K-loop is a T14 2-phase pipeline: reg-stage 6 float4/thread, issue loads
// for tile ks+2 under compute of ks+1; one raw s_barrier per step (counted
// prefetch never drained). Frag layouts identical to the verified r2 kernel.
// ---------------------------------------------------------------------------
__global__ __launch_bounds__(256) void gemm_fused(
    const unsigned short* __restrict__ whl2,  // [8][WSLAB/2]
    const unsigned short* __restrict__ imghl, // [528][8][ISLAB/2]
    const float* __restrict__ bias,
    const int*   __restrict__ geom,           // (24, 59, 704, 2)
    __hip_bfloat16* __restrict__ ctx,         // (24, 704, 80)
    uint2*       __restrict__ plist,
    int*         __restrict__ cntmat,
    int*         __restrict__ ofsmat)
{
    __shared__ __align__(16) unsigned char sS[2][WSLAB + ISLAB];   // 48 KB
    __shared__ float sbias[O_PAD];
    __shared__ int lh[NTILE], lofs[NTILE], lcur[NTILE], sscan[NTILE];

    const int tid  = threadIdx.x;
    const int lane = tid & 63;
    const int wv   = tid >> 6;
    const int s    = wv & 1;                  // px-sub
    const int h    = wv >> 1;                 // o-half
    const int bn   = blockIdx.y;
    const int pt   = blockIdx.x;
    const int p0   = pt * PXT;
    const int blkid = bn * NPXT + pt;

    const unsigned char* wsrc = (const unsigned char*)whl2;
    const unsigned char* isrc = (const unsigned char*)(imghl + (size_t)blkid * 8 * (ISLAB / 2));

    // ---- prologue: issue tile-0 loads, geom loads; init LDS ----
    float4 r[6];
#pragma unroll
    for (int j = 0; j < 5; ++j)
        r[j] = *(const float4*)(wsrc + (size_t)tid * 16 + j * 4096);
    r[5] = *(const float4*)(isrc + (size_t)tid * 16);

    const int m = lane & 15;
    const int q = lane >> 4;
    const int pxl = s * 16 + m;               // local px 0..31
    const int pxg = p0 + pxl;

    unsigned bc[4][4];
    if (h == 0) {                             // depth rows live in h0 waves
        const int2* g2 = (const int2*)geom;
#pragma unroll
        for (int t = 0; t < 4; ++t)
#pragma unroll
            for (int r2 = 0; r2 < 4; ++r2) {
                const int o = 16 * t + 4 * q + r2;
                if (o < D_BINS) {
                    const int2 gg = g2[((size_t)(bn * D_BINS + o)) * PIXELS + pxg];
                    const int tile = (gg.x >> 3) * 8 + (gg.y >> 4);
                    const int cell = (gg.x & 7) * 16 + (gg.y & 15);
                    bc[t][r2] = (unsigned)((tile << 7) | cell);
                }
            }
    }
    if (tid < O_PAD) sbias[tid] = (tid < O_TOT) ? bias[tid] : 0.f;
    if (tid < NTILE) lh[tid] = 0;
    __syncthreads();                          // lh ready (also drains prologue loads)

    if (h == 0) {
#pragma unroll
        for (int t = 0; t < 4; ++t)
#pragma unroll
            for (int r2 = 0; r2 < 4; ++r2)
                if (16 * t + 4 * q + r2 < D_BINS) atomicAdd(&lh[bc[t][r2] >> 7], 1);
    }

    // write tile 0, issue tile 1
#pragma unroll
    for (int j = 0; j < 5; ++j) *(float4*)&sS[0][tid * 16 + j * 4096] = r[j];
    *(float4*)&sS[0][WSLAB + tid * 16] = r[5];
#pragma unroll
    for (int j = 0; j < 5; ++j)
        r[j] = *(const float4*)(wsrc + WSLAB + (size_t)tid * 16 + j * 4096);
    r[5] = *(const float4*)(isrc + ISLAB + (size_t)tid * 16);
    asm volatile("s_waitcnt lgkmcnt(0)" ::: "memory");
    __builtin_amdgcn_s_barrier();
    __builtin_amdgcn_sched_barrier(0);

    f32x4 acc[5];
#pragma unroll
    for (int t = 0; t < 5; ++t) acc[t] = (f32x4){0.f, 0.f, 0.f, 0.f};

    const int g   = lane >> 4;
    const int bpx = pxl;
    const int bgs = g ^ ((bpx >> 1) & 3);
    const int nt  = 5 - h;                    // tiles this wave owns

    for (int ks = 0; ks < 8; ++ks) {
        const unsigned char* base = sS[ks & 1];
        // compute current tile
        const bf16x8 bhi = *(const bf16x8*)&base[WSLAB + bpx * 64 + bgs * 16];
        const bf16x8 blo = *(const bf16x8*)&base[WSLAB + 2048 + bpx * 64 + bgs * 16];
#pragma unroll
        for (int t = 0; t < 5; ++t) {
            if (t < nt) {
                const int row = h * 80 + t * 16 + m;
                const int ags = g ^ ((row >> 1) & 3);
                const bf16x8 ahi = *(const bf16x8*)&base[row * 64 + ags * 16];
                const bf16x8 alo = *(const bf16x8*)&base[9216 + row * 64 + ags * 16];
                acc[t] = __builtin_amdgcn_mfma_f32_16x16x32_bf16(ahi, bhi, acc[t], 0, 0, 0);
                acc[t] = __builtin_amdgcn_mfma_f32_16x16x32_bf16(ahi, blo, acc[t], 0, 0, 0);
                acc[t] = __builtin_amdgcn_mfma_f32_16x16x32_bf16(alo, bhi, acc[t], 0, 0, 0);
            }
        }
        if (ks < 7) {
            __syncthreads();                  // drains r (tile ks+1); sync buf reuse
            unsigned char* nb = sS[(ks + 1) & 1];
#pragma unroll
            for (int j = 0; j < 5; ++j) *(float4*)&nb[tid * 16 + j * 4096] = r[j];
            *(float4*)&nb[WSLAB + tid * 16] = r[5];
            if (ks < 6) {                     // issue tile ks+2 (lands under next compute)
#pragma unroll
                for (int j = 0; j < 5; ++j)
                    r[j] = *(const float4*)(wsrc + (size_t)(ks + 2) * WSLAB + (size_t)tid * 16 + j * 4096);
                r[5] = *(const float4*)(isrc + (size_t)(ks + 2) * ISLAB + (size_t)tid * 16);
            }
            asm volatile("s_waitcnt lgkmcnt(0)" ::: "memory");
            __builtin_amdgcn_s_barrier();
            __builtin_amdgcn_sched_barrier(0);
        }
    }
    __syncthreads();                          // k-loop done; LDS free for overlay

    // ---- bias ----
#pragma unroll
    for (int t = 0; t < 5; ++t)
        if (t < nt)
#pragma unroll
            for (int r2 = 0; r2 < 4; ++r2)
                acc[t][r2] += sbias[h * 80 + t * 16 + q * 4 + r2];

    // ---- softmax (h0 waves): local masked max/sum + shfl over q ----
    float inv = 0.f;
    if (h == 0) {
        float gm = -INFINITY;
#pragma unroll
        for (int t = 0; t < 4; ++t)
#pragma unroll
            for (int r2 = 0; r2 < 4; ++r2)
                if (16 * t + 4 * q + r2 < D_BINS) gm = fmaxf(gm, acc[t][r2]);
        gm = fmaxf(gm, __shfl_xor(gm, 16));
        gm = fmaxf(gm, __shfl_xor(gm, 32));
        float ls = 0.f;
#pragma unroll
        for (int t = 0; t < 4; ++t)
#pragma unroll
            for (int r2 = 0; r2 < 4; ++r2)
                if (16 * t + 4 * q + r2 < D_BINS) {
                    const float e = __expf(acc[t][r2] - gm);
                    acc[t][r2] = e;
                    ls += e;
                }
        ls += __shfl_xor(ls, 16);
        ls += __shfl_xor(ls, 32);
        inv = 1.f / ls;
    }

    // ---- ctx rows -> LDS stage (overlay on sS[0]) ----
    unsigned short* sctx = (unsigned short*)&sS[0][0];   // [32 px][80] bf16
    if (h == 0) {
#pragma unroll
        for (int t = 3; t < 5; ++t)
#pragma unroll
            for (int r2 = 0; r2 < 4; ++r2) {
                const int c = 16 * t + 4 * q + r2 - D_BINS;
                if (c >= 0) sctx[pxl * CTX + c] = f2bf(acc[t][r2]);
            }
    } else {
#pragma unroll
        for (int t = 0; t < 4; ++t)
#pragma unroll
            for (int r2 = 0; r2 < 4; ++r2) {
                const int c = 80 + 16 * t + 4 * q + r2 - D_BINS;
                if (c < CTX) sctx[pxl * CTX + c] = f2bf(acc[t][r2]);
            }
    }
    __syncthreads();

    // ---- 128-wide scan of tile counts ----
    if (tid < NTILE) sscan[tid] = lh[tid];
    __syncthreads();
#pragma unroll
    for (int off = 1; off < NTILE; off <<= 1) {
        const int t = (tid < NTILE && tid >= off) ? sscan[tid - off] : 0;
        __syncthreads();
        if (tid < NTILE) sscan[tid] += t;
        __syncthreads();
    }
    if (tid < NTILE) {
        const int excl = sscan[tid] - lh[tid];
        lofs[tid] = excl;
        lcur[tid] = 0;
        cntmat[(size_t)blkid * NTILE + tid] = lh[tid];
        ofsmat[(size_t)blkid * NTILE + tid] = excl;
    }
    __syncthreads();

    // ---- scatter plist (h0 waves) + ctx writeout (all) ----
    if (h == 0) {
        uint2* dst = plist + (size_t)blkid * EPB;
        const unsigned ctxoff = (unsigned)((bn * PIXELS + pxg) * CTX);
#pragma unroll
        for (int t = 0; t < 4; ++t)
#pragma unroll
            for (int r2 = 0; r2 < 4; ++r2) {
                const int o = 16 * t + 4 * q + r2;
                if (o < D_BINS) {
                    const unsigned u = bc[t][r2];
                    const int tl = (int)(u >> 7);
                    const int pos = lofs[tl] + atomicAdd(&lcur[tl], 1);
                    dst[pos] = make_uint2(__float_as_uint(acc[t][r2] * inv),
                                          (ctxoff << 7) | (u & 127u));
                }
            }
    }
    {
        const char* sb = (const char*)sctx;
        char* gb = (char*)ctx + ((size_t)(bn * PIXELS) + p0) * CTX * 2;
        for (int i = tid; i < PXT * CTX * 2 / 16; i += 256)   // 320 chunks
            *(float4*)(gb + i * 16) = *(const float4*)(sb + i * 16);
    }
}

// ---------------------------------------------------------------------------
// Kernel 2 (gather): unchanged from the verified r2 version.
// ---------------------------------------------------------------------------
__global__ __launch_bounds__(1024) void gather_kernel(
    const uint2* __restrict__ plist,
    const int*   __restrict__ cntmat,
    const int*   __restrict__ ofsmat,
    const unsigned short* __restrict__ ctx,
    float*       __restrict__ out)
{
    __shared__ float sacc[CTX][TCELLS + 1];
    __shared__ uint2 bufB[CAPP];
    __shared__ int sg[256];
    __shared__ int segcnt[SEGS], segofs[SEGS];
    __shared__ int cellcnt[TCELLS], celloff[TCELLS], cellcur[TCELLS], sc[TCELLS];
    uint2* bufA = (uint2*)sacc;

    const int tid    = threadIdx.x;
    const int wv     = tid >> 6;
    const int lane   = tid & 63;
    const int bucket = blockIdx.x;
    const int b      = bucket >> 7;
    const int tile   = bucket & 127;
    const int blk0   = b * SEGS;

    if (tid < 256) {
        const int c = (tid < SEGS) ? cntmat[(size_t)(blk0 + tid) * NTILE + tile] : 0;
        sg[tid] = c;
        if (tid < SEGS) segcnt[tid] = c;
    }
    __syncthreads();
#pragma unroll
    for (int off = 1; off < 256; off <<= 1) {
        const int t = (tid < 256 && tid >= off) ? sg[tid - off] : 0;
        __syncthreads();
        if (tid < 256) sg[tid] += t;
        __syncthreads();
    }
    if (tid < SEGS) segofs[tid] = sg[tid] - segcnt[tid];
    __syncthreads();
    const int total = sg[255];

    {
        const int sub = lane >> 4;
        const int sl  = lane & 15;
        for (int sgi = wv * 4 + sub; sgi < SEGS; sgi += 64) {
            const int n = segcnt[sgi];
            if (!n) continue;
            const int dstb = segofs[sgi];
            const uint2* sp = plist + (size_t)(blk0 + sgi) * EPB
                              + ofsmat[(size_t)(blk0 + sgi) * NTILE + tile];
            for (int i = sl; i < n; i += 16) {
                const int d = dstb + i;
                if (d < CAP) bufA[d] = sp[i];
            }
        }
    }
    const int ncap = (total < CAP) ? total : CAP;
    __syncthreads();

    if (tid < TCELLS) cellcnt[tid] = 0;
    __syncthreads();
    for (int i = tid; i < ncap; i += 1024)
        atomicAdd(&cellcnt[bufA[i].y & 127u], 1);
    __syncthreads();
    if (tid < TCELLS) sc[tid] = (cellcnt[tid] + 7) & ~7;
    __syncthreads();
#pragma unroll
    for (int off = 1; off < TCELLS; off <<= 1) {
        const int t = (tid < TCELLS && tid >= off) ? sc[tid - off] : 0;
        __syncthreads();
        if (tid < TCELLS) sc[tid] += t;
        __syncthreads();
    }
    if (tid < TCELLS) {
        celloff[tid] = sc[tid] - ((cellcnt[tid] + 7) & ~7);
        cellcur[tid] = 0;
    }
    __syncthreads();
    const int padtotal = sc[TCELLS - 1];
    for (int i = tid; i < padtotal; i += 1024) bufB[i] = make_uint2(0u, 0u);
    __syncthreads();
    for (int i = tid; i < ncap; i += 1024) {
        const uint2 e = bufA[i];
        const int c = (int)(e.y & 127u);
        bufB[celloff[c] + atomicAdd(&cellcur[c], 1)] = e;
    }
    __syncthreads();

    for (int c = wv; c < TCELLS; c += 16) {
        const int s0 = celloff[c];
        const int pc = (cellcnt[c] + 7) & ~7;
        float a0 = 0.f, a1 = 0.f;
        for (int i = 0; i < pc; i += 8) {
            uint2 e[8];
#pragma unroll
            for (int r = 0; r < 8; ++r) e[r] = bufB[s0 + i + r];
            if (lane < 40) {
                unsigned u[8];
#pragma unroll
                for (int r = 0; r < 8; ++r)
                    u[r] = *(const unsigned*)(ctx + (e[r].y >> 7) + 2 * lane);
#pragma unroll
                for (int r = 0; r < 8; ++r) {
                    const float d  = __uint_as_float(e[r].x);
                    a0 += d * __uint_as_float(u[r] << 16);
                    a1 += d * __uint_as_float(u[r] & 0xffff0000u);
                }
            }
        }
        if (lane < 40) {
            sacc[2 * lane][c]     = a0;
            sacc[2 * lane + 1][c] = a1;
        }
    }

    if (total > CAP) {
        for (int sgi = 0; sgi < SEGS; ++sgi) {
            const int dstb = segofs[sgi];
            const int n    = segcnt[sgi];
            if (dstb + n <= CAP) continue;
            const uint2* sp = plist + (size_t)(blk0 + sgi) * EPB
                              + ofsmat[(size_t)(blk0 + sgi) * NTILE + tile];
            const int i0 = (CAP > dstb) ? (CAP - dstb) : 0;
            for (int i = i0; i < n; ++i) {
                const uint2 e = sp[i];
                const int c = (int)(e.y & 127u);
                if ((c & 15) == wv && lane < 40) {
                    const unsigned u = *(const unsigned*)(ctx + (e.y >> 7) + 2 * lane);
                    const float dep = __uint_as_float(e.x);
                    sacc[2 * lane][c]     += dep * __uint_as_float(u << 16);
                    sacc[2 * lane + 1][c] += dep * __uint_as_float(u & 0xffff0000u);
                }
            }
        }
    }
    __syncthreads();

    const int tl = bucket & 127;
    const int tr = tl >> 3;
    const int tc = tl & 7;
    const int c0  = tid >> 4;
    const int col = tid & 15;
#pragma unroll
    for (int cc = c0; cc < CTX; cc += 64) {
#pragma unroll
        for (int r = 0; r < 8; ++r) {
            out[((size_t)(b * CTX + cc)) * BEVHW + (tr * 8 + r) * 128 + tc * 16 + col]
                = sacc[cc][r * 16 + col];
        }
    }
}

extern "C" void kernel_launch(void* const* d_in, const int* in_sizes, int n_in,
                              void* d_out, int out_size, void* d_ws, size_t ws_size,
                              hipStream_t stream)
{
    const float* img  = (const float*)d_in[0];
    const float* w    = (const float*)d_in[4];
    const float* bias = (const float*)d_in[5];
    const int*   geom = (const int*)d_in[6];
    float*       out  = (float*)d_out;

    float* ws = (float*)d_ws;
    unsigned short* whl2  = (unsigned short*)(ws + WHL_OFF);
    unsigned short* imghl = (unsigned short*)(ws + IMGHL_OFF);
    __hip_bfloat16* ctx = (__hip_bfloat16*)(ws + CTX_OFF);
    int*   cntmat = (int*)(ws + CNTMAT_OFF);
    int*   ofsmat = (int*)(ws + OFSMAT_OFF);
    uint2* plist  = (uint2*)(ws + PLIST_OFF);

    // 0. pre-convert W and img to bf16 hi/lo in DMA-ready swizzled layout
    prep_kernel<<<O_PAD + NBLK, 256, 0, stream>>>(img, w, whl2, imghl);

    // 1. pipelined MFMA GEMM + fused bias/softmax/binning epilogue
    {
        dim3 grid(NPXT, BNPAIR);   // 22 x 24 = 528 blocks, 256 threads
        gemm_fused<<<grid, 256, 0, stream>>>(whl2, imghl, bias, geom, ctx,
                                             plist, cntmat, ofsmat);
    }

    // 2. fused cell-sort + gather per bucket, coalesced (B,C,H,W) writes
    gather_kernel<<<NBUCKET, 1024, 0, stream>>>(plist, cntmat, ofsmat,
                                                (const unsigned short*)ctx, out);
}

// Round 4
// 140.644 us; speedup vs baseline: 1.2480x; 1.2480x over previous
//
#include <hip/hip_runtime.h>
#include <hip/hip_bf16.h>
#include <math.h>

// Problem constants
#define D_BINS 59
#define CTX    80
#define O_TOT  139
#define K_CIN  256
#define PIXELS 704
#define BNPAIR 24
#define BEVHW  16384
#define NBATCH 4

// BEV binning: tile = 8 rows x 16 cols -> 128 cells, 128 tiles/batch.
#define NTILE   128
#define NBUCKET (NBATCH * NTILE)   // 512
#define TCELLS  128

// producer blocks: 16 px per one-wave block; 24 bn * 44 ptiles * 2 roles.
#define PXT    16
#define NPXT   44                  // 704/16
#define NBLK   (BNPAIR * NPXT)     // 1056 regions
#define SEGS   (6 * NPXT)          // 264 segments per bucket
#define EPB    (PXT * D_BINS)      // 944 entries per region

#define CAP    2816
#define CAPP   (CAP + TCELLS * 7)

// Workspace layout (4B units)
#define WHL_OFF    0
#define WHL_F      36864                           // 2 planes * 144*256 bf16
#define CTX_OFF    (WHL_OFF + WHL_F)
#define CTX_F      (BNPAIR * PIXELS * CTX / 2)     // 675,840
#define CNTMAT_OFF (CTX_OFF + CTX_F)
#define OFSMAT_OFF (CNTMAT_OFF + NBLK * NTILE)
#define PLIST_OFF  (OFSMAT_OFF + NBLK * NTILE)     // even -> uint2 aligned

typedef __attribute__((ext_vector_type(8))) short bf16x8;
typedef __attribute__((ext_vector_type(4))) float f32x4;

__device__ __forceinline__ unsigned short f2bf(float v) {
    __hip_bfloat16 h = __float2bfloat16(v);   // RNE
    return *reinterpret_cast<unsigned short*>(&h);
}
__device__ __forceinline__ float bf2f(unsigned short u) {
    return __uint_as_float(((unsigned)u) << 16);
}

// ---------------------------------------------------------------------------
// Kernel 0 (wsplit): W (139x256 fp32) -> bf16 hi/lo planes [144][256], pad=0.
// Plain row-major (no swizzle needed: fragments are read per-lane from L2).
// ---------------------------------------------------------------------------
__global__ __launch_bounds__(256) void wsplit_kernel(
    const float* __restrict__ w, unsigned short* __restrict__ whl)
{
    const int row = blockIdx.x;        // 0..143
    const int col = threadIdx.x;       // 0..255
    const float v = (row < O_TOT) ? w[(size_t)row * K_CIN + col] : 0.f;
    const unsigned short hi = f2bf(v);
    const unsigned short lo = f2bf(v - bf2f(hi));
    whl[row * K_CIN + col]         = hi;
    whl[36864 + row * K_CIN + col] = lo;
}

// ---------------------------------------------------------------------------
// K-loop: per-wave MFMA with operands loaded straight from global (no LDS,
// no barriers). Fragment mapping identical to the r2-verified kernel:
// A lane(m,g): W[row=(T0+t)*16+m][k=ks*32+8g..+8]; B lane(m,g):
// img[k=ks*32+8g+j][px=p0+m] converted to bf16 hi/lo in-register.
// MFMA order (ahi,bhi),(ahi,blo),(alo,bhi) -> bitwise == r2 numerics.
// ---------------------------------------------------------------------------
template<int NT, int T0>
__device__ __forceinline__ void kloop(
    const float* __restrict__ ib, const unsigned short* __restrict__ whl,
    int pxg, int m, int g, f32x4* acc)
{
#pragma unroll 2
    for (int ks = 0; ks < 8; ++ks) {
        float bv[8];
#pragma unroll
        for (int j = 0; j < 8; ++j)
            bv[j] = ib[(size_t)(ks * 32 + 8 * g + j) * PIXELS + pxg];
        bf16x8 bhi, blo;
#pragma unroll
        for (int j = 0; j < 8; ++j) {
            const unsigned short h = f2bf(bv[j]);
            bhi[j] = (short)h;
            blo[j] = (short)f2bf(bv[j] - bf2f(h));
        }
#pragma unroll
        for (int t = 0; t < NT; ++t) {
            const int row = (T0 + t) * 16 + m;
            const bf16x8 ahi = *(const bf16x8*)&whl[(size_t)row * K_CIN + ks * 32 + g * 8];
            const bf16x8 alo = *(const bf16x8*)&whl[36864 + (size_t)row * K_CIN + ks * 32 + g * 8];
            acc[t] = __builtin_amdgcn_mfma_f32_16x16x32_bf16(ahi, bhi, acc[t], 0, 0, 0);
            acc[t] = __builtin_amdgcn_mfma_f32_16x16x32_bf16(ahi, blo, acc[t], 0, 0, 0);
            acc[t] = __builtin_amdgcn_mfma_f32_16x16x32_bf16(alo, bhi, acc[t], 0, 0, 0);
        }
    }
}

// ---------------------------------------------------------------------------
// Kernel 1: one-wave blocks, ZERO __syncthreads. z=0: depth (tiles 0..3,
// softmax + binning + plist scatter, all wave-local). z=1: ctx (tiles 3..8,
// bf16 ctx writeout via small LDS stage). 2112 blocks -> stalls overlap.
// ---------------------------------------------------------------------------
__global__ __launch_bounds__(64) void gemm_fused(
    const float* __restrict__ img,            // (24, 256, 704)
    const unsigned short* __restrict__ whl,   // 2 planes [144][256] bf16 bits
    const float* __restrict__ bias,           // (139)
    const int*   __restrict__ geom,           // (24, 59, 704, 2)
    __hip_bfloat16* __restrict__ ctx,         // (24, 704, 80) bf16
    uint2*       __restrict__ plist,          // [NBLK][EPB]
    int*         __restrict__ cntmat,         // [NBLK][NTILE]
    int*         __restrict__ ofsmat)         // [NBLK][NTILE]
{
    const int lane = threadIdx.x;
    const int m    = lane & 15;
    const int g    = lane >> 4;                // == q for C-rows
    const int pt   = blockIdx.x;               // 0..43
    const int bn   = blockIdx.y;               // 0..23
    const int p0   = pt * PXT;
    const int pxg  = p0 + m;
    const int blkid = bn * NPXT + pt;
    const float* ib = img + (size_t)bn * K_CIN * PIXELS;

    if (blockIdx.z == 0) {
        // ================= depth role =================
        __shared__ int lh[NTILE], lofs[NTILE], lcur[NTILE];
        f32x4 acc[4];
#pragma unroll
        for (int t = 0; t < 4; ++t) acc[t] = (f32x4){0.f, 0.f, 0.f, 0.f};
        kloop<4, 0>(ib, whl, pxg, m, g, acc);

        // geom loads issued before the softmax chain (latency overlap)
        const int2* g2 = (const int2*)geom;
        int2 gg[4][4];
#pragma unroll
        for (int t = 0; t < 4; ++t)
#pragma unroll
            for (int r = 0; r < 4; ++r) {
                const int o = 16 * t + 4 * g + r;
                if (o < D_BINS)
                    gg[t][r] = g2[((size_t)(bn * D_BINS + o)) * PIXELS + pxg];
            }
        lh[lane] = 0; lh[lane + 64] = 0;
        lcur[lane] = 0; lcur[lane + 64] = 0;

        // bias (rows 0..63 all < 139)
#pragma unroll
        for (int t = 0; t < 4; ++t)
#pragma unroll
            for (int r = 0; r < 4; ++r) acc[t][r] += bias[16 * t + 4 * g + r];

        // softmax over o<59 (identical op order to verified r2 kernel)
        float gm = -INFINITY;
#pragma unroll
        for (int t = 0; t < 4; ++t)
#pragma unroll
            for (int r = 0; r < 4; ++r)
                if (16 * t + 4 * g + r < D_BINS) gm = fmaxf(gm, acc[t][r]);
        gm = fmaxf(gm, __shfl_xor(gm, 16));
        gm = fmaxf(gm, __shfl_xor(gm, 32));
        float ls = 0.f;
#pragma unroll
        for (int t = 0; t < 4; ++t)
#pragma unroll
            for (int r = 0; r < 4; ++r)
                if (16 * t + 4 * g + r < D_BINS) {
                    const float e = __expf(acc[t][r] - gm);
                    acc[t][r] = e;
                    ls += e;
                }
        ls += __shfl_xor(ls, 16);
        ls += __shfl_xor(ls, 32);
        const float inv = 1.f / ls;

        // bucket/cell codes + wave-local histogram (LDS atomics, no barrier)
        unsigned uc[4][4];
#pragma unroll
        for (int t = 0; t < 4; ++t)
#pragma unroll
            for (int r = 0; r < 4; ++r) {
                const int o = 16 * t + 4 * g + r;
                if (o < D_BINS) {
                    const int2 q = gg[t][r];
                    const int tile = (q.x >> 3) * 8 + (q.y >> 4);
                    const int cell = (q.x & 7) * 16 + (q.y & 15);
                    uc[t][r] = (unsigned)((tile << 7) | cell);
                    atomicAdd(&lh[tile], 1);
                }
            }

        // in-wave scan of 128 tile counts: lane owns tiles 2l, 2l+1
        const int l2 = 2 * lane;
        const int a = lh[l2];
        const int b = lh[l2 + 1];
        const int p = a + b;
        int incl = p;
#pragma unroll
        for (int off = 1; off < 64; off <<= 1) {
            const int t = __shfl_up(incl, off);
            if (lane >= off) incl += t;
        }
        const int excl = incl - p;
        lofs[l2]     = excl;
        lofs[l2 + 1] = excl + a;
        *(int2*)&cntmat[(size_t)blkid * NTILE + l2] = make_int2(a, b);
        *(int2*)&ofsmat[(size_t)blkid * NTILE + l2] = make_int2(excl, excl + a);

        // scatter this lane's own points
        uint2* dst = plist + (size_t)blkid * EPB;
        const unsigned ctxoff = (unsigned)((bn * PIXELS + pxg) * CTX);
#pragma unroll
        for (int t = 0; t < 4; ++t)
#pragma unroll
            for (int r = 0; r < 4; ++r) {
                const int o = 16 * t + 4 * g + r;
                if (o < D_BINS) {
                    const unsigned u = uc[t][r];
                    const int tl = (int)(u >> 7);
                    const int pos = lofs[tl] + atomicAdd(&lcur[tl], 1);
                    dst[pos] = make_uint2(__float_as_uint(acc[t][r] * inv),
                                          (ctxoff << 7) | (u & 127u));
                }
            }
    } else {
        // ================= ctx role =================
        __shared__ unsigned short sctx[PXT][CTX];   // 2.5 KB
        f32x4 acc[6];
#pragma unroll
        for (int t = 0; t < 6; ++t) acc[t] = (f32x4){0.f, 0.f, 0.f, 0.f};
        kloop<6, 3>(ib, whl, pxg, m, g, acc);

#pragma unroll
        for (int t = 0; t < 6; ++t)
#pragma unroll
            for (int r = 0; r < 4; ++r) {
                const int o = (3 + t) * 16 + 4 * g + r;      // 48..143
                const int c = o - D_BINS;                    // -11..84
                if (c >= 0 && c < CTX)
                    sctx[m][c] = f2bf(acc[t][r] + bias[o]);
            }
        // coalesced writeout (wave-local LDS: compiler orders via lgkmcnt)
        const char* sb = (const char*)sctx;
        char* gb = (char*)ctx + ((size_t)(bn * PIXELS) + p0) * CTX * 2;
#pragma unroll
        for (int i = lane; i < PXT * CTX * 2 / 16; i += 64)   // 160 chunks
            *(float4*)(gb + i * 16) = *(const float4*)(sb + i * 16);
    }
}

// ---------------------------------------------------------------------------
// Kernel 2 (gather): one block per bucket. 264 segments (~7.4 pts each),
// copied by 8-lane subgroups -> bufA -> cell-sort into bufB (pad-to-8).
// Lane l<40 owns channel pair (2l,2l+1), one u32 (2xbf16) load per point.
// ---------------------------------------------------------------------------
__global__ __launch_bounds__(1024) void gather_kernel(
    const uint2* __restrict__ plist,
    const int*   __restrict__ cntmat,
    const int*   __restrict__ ofsmat,
    const unsigned short* __restrict__ ctx,
    float*       __restrict__ out)
{
    __shared__ float sacc[CTX][TCELLS + 1];   // 41.3 KB
    __shared__ uint2 bufB[CAPP];              // 29 KB
    __shared__ int sg[512];
    __shared__ int segcnt[SEGS], segofs[SEGS];
    __shared__ int cellcnt[TCELLS], celloff[TCELLS], cellcur[TCELLS], sc[TCELLS];
    uint2* bufA = (uint2*)sacc;

    const int tid    = threadIdx.x;
    const int wv     = tid >> 6;
    const int lane   = tid & 63;
    const int bucket = blockIdx.x;
    const int b      = bucket >> 7;
    const int tile   = bucket & 127;
    const int blk0   = b * SEGS;

    // scan of 264 segment counts (padded to 512)
    if (tid < 512) {
        const int c = (tid < SEGS) ? cntmat[(size_t)(blk0 + tid) * NTILE + tile] : 0;
        sg[tid] = c;
        if (tid < SEGS) segcnt[tid] = c;
    }
    __syncthreads();
#pragma unroll
    for (int off = 1; off < 512; off <<= 1) {
        const int t = (tid < 512 && tid >= off) ? sg[tid - off] : 0;
        __syncthreads();
        if (tid < 512) sg[tid] += t;
        __syncthreads();
    }
    if (tid < SEGS) segofs[tid] = sg[tid] - segcnt[tid];
    __syncthreads();
    const int total = sg[511];

    // segment copy: 8-lane subgroups (128 subgroups over 264 segs)
    {
        const int sub = lane >> 3;
        const int sl  = lane & 7;
        for (int sgi = wv * 8 + sub; sgi < SEGS; sgi += 128) {
            const int n = segcnt[sgi];
            if (!n) continue;
            const int dstb = segofs[sgi];
            const uint2* sp = plist + (size_t)(blk0 + sgi) * EPB
                              + ofsmat[(size_t)(blk0 + sgi) * NTILE + tile];
            for (int i = sl; i < n; i += 8) {
                const int d = dstb + i;
                if (d < CAP) bufA[d] = sp[i];
            }
        }
    }
    const int ncap = (total < CAP) ? total : CAP;
    __syncthreads();

    // cell histogram
    if (tid < TCELLS) cellcnt[tid] = 0;
    __syncthreads();
    for (int i = tid; i < ncap; i += 1024)
        atomicAdd(&cellcnt[bufA[i].y & 127u], 1);
    __syncthreads();
    if (tid < TCELLS) sc[tid] = (cellcnt[tid] + 7) & ~7;
    __syncthreads();
#pragma unroll
    for (int off = 1; off < TCELLS; off <<= 1) {
        const int t = (tid < TCELLS && tid >= off) ? sc[tid - off] : 0;
        __syncthreads();
        if (tid < TCELLS) sc[tid] += t;
        __syncthreads();
    }
    if (tid < TCELLS) {
        celloff[tid] = sc[tid] - ((cellcnt[tid] + 7) & ~7);
        cellcur[tid] = 0;
    }
    __syncthreads();
    const int padtotal = sc[TCELLS - 1];
    for (int i = tid; i < padtotal; i += 1024) bufB[i] = make_uint2(0u, 0u);
    __syncthreads();
    for (int i = tid; i < ncap; i += 1024) {
        const uint2 e = bufA[i];
        const int c = (int)(e.y & 127u);
        bufB[celloff[c] + atomicAdd(&cellcur[c], 1)] = e;
    }
    __syncthreads();   // bufA dead; sacc live

    for (int c = wv; c < TCELLS; c += 16) {
        const int s0 = celloff[c];
        const int pc = (cellcnt[c] + 7) & ~7;
        float a0 = 0.f, a1 = 0.f;
        for (int i = 0; i < pc; i += 8) {
            uint2 e[8];
#pragma unroll
            for (int r = 0; r < 8; ++r) e[r] = bufB[s0 + i + r];
            if (lane < 40) {
                unsigned u[8];
#pragma unroll
                for (int r = 0; r < 8; ++r)
                    u[r] = *(const unsigned*)(ctx + (e[r].y >> 7) + 2 * lane);
#pragma unroll
                for (int r = 0; r < 8; ++r) {
                    const float d  = __uint_as_float(e[r].x);
                    a0 += d * __uint_as_float(u[r] << 16);
                    a1 += d * __uint_as_float(u[r] & 0xffff0000u);
                }
            }
        }
        if (lane < 40) {
            sacc[2 * lane][c]     = a0;
            sacc[2 * lane + 1][c] = a1;
        }
    }

    // slow path for bucket overflow (correctness only)
    if (total > CAP) {
        for (int sgi = 0; sgi < SEGS; ++sgi) {
            const int dstb = segofs[sgi];
            const int n    = segcnt[sgi];
            if (dstb + n <= CAP) continue;
            const uint2* sp = plist + (size_t)(blk0 + sgi) * EPB
                              + ofsmat[(size_t)(blk0 + sgi) * NTILE + tile];
            const int i0 = (CAP > dstb) ? (CAP - dstb) : 0;
            for (int i = i0; i < n; ++i) {
                const uint2 e = sp[i];
                const int c = (int)(e.y & 127u);
                if ((c & 15) == wv && lane < 40) {
                    const unsigned u = *(const unsigned*)(ctx + (e.y >> 7) + 2 * lane);
                    const float dep = __uint_as_float(e.x);
                    sacc[2 * lane][c]     += dep * __uint_as_float(u << 16);
                    sacc[2 * lane + 1][c] += dep * __uint_as_float(u & 0xffff0000u);
                }
            }
        }
    }
    __syncthreads();

    // epilogue: full 64B line writes to (B,C,H,W)
    const int tl = bucket & 127;
    const int tr = tl >> 3;
    const int tc = tl & 7;
    const int c0  = tid >> 4;
    const int col = tid & 15;
#pragma unroll
    for (int cc = c0; cc < CTX; cc += 64) {
#pragma unroll
        for (int r = 0; r < 8; ++r) {
            out[((size_t)(b * CTX + cc)) * BEVHW + (tr * 8 + r) * 128 + tc * 16 + col]
                = sacc[cc][r * 16 + col];
        }
    }
}

extern "C" void kernel_launch(void* const* d_in, const int* in_sizes, int n_in,
                              void* d_out, int out_size, void* d_ws, size_t ws_size,
                              hipStream_t stream)
{
    const float* img  = (const float*)d_in[0];
    const float* w    = (const float*)d_in[4];
    const float* bias = (const float*)d_in[5];
    const int*   geom = (const int*)d_in[6];
    float*       out  = (float*)d_out;

    float* ws = (float*)d_ws;
    unsigned short* whl = (unsigned short*)(ws + WHL_OFF);
    __hip_bfloat16* ctx = (__hip_bfloat16*)(ws + CTX_OFF);
    int*   cntmat = (int*)(ws + CNTMAT_OFF);
    int*   ofsmat = (int*)(ws + OFSMAT_OFF);
    uint2* plist  = (uint2*)(ws + PLIST_OFF);

    // 0. W -> bf16 hi/lo planes (147 KB, L2-resident)
    wsplit_kernel<<<144, 256, 0, stream>>>(w, whl);

    // 1. barrier-free one-wave MFMA blocks: z=0 depth+binning, z=1 ctx
    {
        dim3 grid(NPXT, BNPAIR, 2);   // 2112 blocks x 64 threads
        gemm_fused<<<grid, 64, 0, stream>>>(img, whl, bias, geom, ctx,
                                            plist, cntmat, ofsmat);
    }

    // 2. fused cell-sort + gather per bucket, coalesced (B,C,H,W) writes
    gather_kernel<<<NBUCKET, 1024, 0, stream>>>(plist, cntmat, ofsmat,
                                                (const unsigned short*)ctx, out);
}